// Round 15
// baseline (3029.982 us; speedup 1.0000x reference)
//
#include <hip/hip_runtime.h>
#include <cstdint>
#include <cstddef>

#define NROWS 12288
#define FDIM 768
#define HDIM 512
#define ODIM 256
#define TOPK 31                // knn_k + 1

// ---------------------------------------------------------------------------
// 64-tile fp32 GEMM (OpenBLAS-bitwise: serial ascending-k FMA chains, fold
// at K/2), swizzled LDS k-rows (conflict-free). Used for layer 3 (small N).
// ---------------------------------------------------------------------------
template<bool RELU>
__global__ __launch_bounds__(256)
void gemm_nt_serial(const float* __restrict__ A, const float* __restrict__ B,
                    const float* __restrict__ bias, float* __restrict__ C,
                    int Nout, int K)
{
  __shared__ float As[32][68];
  __shared__ float Bs[32][68];
  const int tid = threadIdx.x;
  const int tx = tid & 15, ty = tid >> 4;
  const int r0 = blockIdx.y * 64, c0 = blockIdx.x * 64;
  float acc[4][4] = {};
  float accC[4][4];
  bool first = true;
  const int Khalf = K / 2;

  for (int k0 = 0; k0 < K; k0 += 32) {
#pragma unroll
    for (int l = 0; l < 2; ++l) {
      const int lin = l * 256 + tid;
      const int row = lin >> 3, kq = lin & 7;
      const float4 a = *(const float4*)(A + (size_t)(r0 + row) * K + k0 + kq * 4);
      As[kq + 0][row] = a.x; As[kq + 8][row] = a.y;
      As[kq + 16][row] = a.z; As[kq + 24][row] = a.w;
      const float4 b = *(const float4*)(B + (size_t)(c0 + row) * K + k0 + kq * 4);
      Bs[kq + 0][row] = b.x; Bs[kq + 8][row] = b.y;
      Bs[kq + 16][row] = b.z; Bs[kq + 24][row] = b.w;
    }
    __syncthreads();
#pragma unroll
    for (int kk = 0; kk < 32; ++kk) {
      const int kp = ((kk & 3) << 3) | (kk >> 2);
      const float4 av = *(const float4*)&As[kp][ty * 4];
      const float4 bv = *(const float4*)&Bs[kp][tx * 4];
      const float a4[4] = {av.x, av.y, av.z, av.w};
      const float b4[4] = {bv.x, bv.y, bv.z, bv.w};
#pragma unroll
      for (int i = 0; i < 4; ++i)
#pragma unroll
        for (int j = 0; j < 4; ++j)
          acc[i][j] = fmaf(a4[i], b4[j], acc[i][j]);
    }
    __syncthreads();

    if ((k0 + 32 == Khalf) || (k0 + 32 == K)) {
#pragma unroll
      for (int i = 0; i < 4; ++i)
#pragma unroll
        for (int j = 0; j < 4; ++j) {
          accC[i][j] = first ? acc[i][j] : __fadd_rn(accC[i][j], acc[i][j]);
          acc[i][j] = 0.f;
        }
      first = false;
    }
  }

  const float4 bq = *(const float4*)(bias + c0 + tx * 4);
  const float bb[4] = {bq.x, bq.y, bq.z, bq.w};
#pragma unroll
  for (int i = 0; i < 4; ++i) {
    float v[4];
#pragma unroll
    for (int j = 0; j < 4; ++j) {
      v[j] = __fadd_rn(accC[i][j], bb[j]);
      if (RELU) v[j] = fmaxf(v[j], 0.f);
    }
    float4 o; o.x = v[0]; o.y = v[1]; o.z = v[2]; o.w = v[3];
    *(float4*)(C + (size_t)(r0 + ty * 4 + i) * Nout + c0 + tx * 4) = o;
  }
}

// ---------------------------------------------------------------------------
// 128-tile fp32 GEMM, 8x8 micro (split cols tx*4 / 64+tx*4), swizzled LDS,
// OpenBLAS-bitwise fold at K/2. Used for layers 1 and 2.
// ---------------------------------------------------------------------------
template<bool RELU>
__global__ __launch_bounds__(256)
void gemm_big_nt(const float* __restrict__ A, const float* __restrict__ B,
                 const float* __restrict__ bias, float* __restrict__ C,
                 int Nout, int K)
{
  __shared__ float As[32][132];
  __shared__ float Bs[32][132];
  const int tid = threadIdx.x;
  const int tx = tid & 15, ty = tid >> 4;
  const int r0 = blockIdx.y * 128, c0 = blockIdx.x * 128;
  float acc[8][8] = {};
  float accC[8][8];
  bool first = true;
  const int Khalf = K / 2;

  for (int k0 = 0; k0 < K; k0 += 32) {
#pragma unroll
    for (int l = 0; l < 4; ++l) {
      const int lin = l * 256 + tid;
      const int row = lin >> 3, q = lin & 7;
      const float4 a = *(const float4*)(A + (size_t)(r0 + row) * K + k0 + q * 4);
      As[q + 0][row] = a.x; As[q + 8][row] = a.y;
      As[q + 16][row] = a.z; As[q + 24][row] = a.w;
      const float4 b = *(const float4*)(B + (size_t)(c0 + row) * K + k0 + q * 4);
      Bs[q + 0][row] = b.x; Bs[q + 8][row] = b.y;
      Bs[q + 16][row] = b.z; Bs[q + 24][row] = b.w;
    }
    __syncthreads();
#pragma unroll
    for (int kk = 0; kk < 32; ++kk) {
      const int kp = ((kk & 3) << 3) | (kk >> 2);
      float a8[8], b8[8];
      *(float4*)&a8[0] = *(const float4*)&As[kp][ty * 8];
      *(float4*)&a8[4] = *(const float4*)&As[kp][ty * 8 + 4];
      *(float4*)&b8[0] = *(const float4*)&Bs[kp][tx * 4];
      *(float4*)&b8[4] = *(const float4*)&Bs[kp][64 + tx * 4];
#pragma unroll
      for (int i = 0; i < 8; ++i)
#pragma unroll
        for (int j = 0; j < 8; ++j)
          acc[i][j] = fmaf(a8[i], b8[j], acc[i][j]);
    }
    __syncthreads();

    if ((k0 + 32 == Khalf) || (k0 + 32 == K)) {
#pragma unroll
      for (int i = 0; i < 8; ++i)
#pragma unroll
        for (int j = 0; j < 8; ++j) {
          accC[i][j] = first ? acc[i][j] : __fadd_rn(accC[i][j], acc[i][j]);
          acc[i][j] = 0.f;
        }
      first = false;
    }
  }

  const float4 bq0 = *(const float4*)(bias + c0 + tx * 4);
  const float4 bq1 = *(const float4*)(bias + c0 + 64 + tx * 4);
  const float bb[8] = {bq0.x, bq0.y, bq0.z, bq0.w, bq1.x, bq1.y, bq1.z, bq1.w};
#pragma unroll
  for (int i = 0; i < 8; ++i) {
    float v[8];
#pragma unroll
    for (int j = 0; j < 8; ++j) {
      v[j] = __fadd_rn(accC[i][j], bb[j]);
      if (RELU) v[j] = fmaxf(v[j], 0.f);
    }
    float* dst = C + (size_t)(r0 + ty * 8 + i) * Nout + c0;
    float4 o0; o0.x = v[0]; o0.y = v[1]; o0.z = v[2]; o0.w = v[3];
    float4 o1; o1.x = v[4]; o1.y = v[5]; o1.z = v[6]; o1.w = v[7];
    *(float4*)(dst + tx * 4) = o0;
    *(float4*)(dst + 64 + tx * 4) = o1;
  }
}

// ---------------------------------------------------------------------------
// Row L2-normalize replicating numpy pairwise_sum bitwise (n=256) + IEEE
// sqrt/divide. One thread per row.
// ---------------------------------------------------------------------------
__global__ __launch_bounds__(64)
void l2norm_np(float* __restrict__ X)
{
  const int row = blockIdx.x * 64 + threadIdx.x;
  float* x = X + (size_t)row * ODIM;

  float S = 0.f;
#pragma unroll
  for (int h = 0; h < 2; ++h) {
    const float* a = x + h * 128;
    float r0 = __fmul_rn(a[0], a[0]);
    float r1 = __fmul_rn(a[1], a[1]);
    float r2 = __fmul_rn(a[2], a[2]);
    float r3 = __fmul_rn(a[3], a[3]);
    float r4 = __fmul_rn(a[4], a[4]);
    float r5 = __fmul_rn(a[5], a[5]);
    float r6 = __fmul_rn(a[6], a[6]);
    float r7 = __fmul_rn(a[7], a[7]);
    for (int i = 8; i < 128; i += 8) {
      r0 = __fadd_rn(r0, __fmul_rn(a[i + 0], a[i + 0]));
      r1 = __fadd_rn(r1, __fmul_rn(a[i + 1], a[i + 1]));
      r2 = __fadd_rn(r2, __fmul_rn(a[i + 2], a[i + 2]));
      r3 = __fadd_rn(r3, __fmul_rn(a[i + 3], a[i + 3]));
      r4 = __fadd_rn(r4, __fmul_rn(a[i + 4], a[i + 4]));
      r5 = __fadd_rn(r5, __fmul_rn(a[i + 5], a[i + 5]));
      r6 = __fadd_rn(r6, __fmul_rn(a[i + 6], a[i + 6]));
      r7 = __fadd_rn(r7, __fmul_rn(a[i + 7], a[i + 7]));
    }
    const float half = __fadd_rn(
        __fadd_rn(__fadd_rn(r0, r1), __fadd_rn(r2, r3)),
        __fadd_rn(__fadd_rn(r4, r5), __fadd_rn(r6, r7)));
    S = (h == 0) ? half : __fadd_rn(S, half);
  }

  const float d = fmaxf(__fsqrt_rn(S), 1e-12f);
  for (int k = 0; k < ODIM; ++k) x[k] = __fdiv_rn(x[k], d);
}

// ---------------------------------------------------------------------------
// SYMMETRIC fp32 sim GEMM: S = E @ E^T, upper-triangle blocks (bx >= by).
// Off-diagonal tiles mirrored directly from registers (8 consecutive rows
// per owned column -> two float4 stores). fmaf(a,b,c)==fmaf(b,a,c) ->
// mirrored chain bit-identical.
// ---------------------------------------------------------------------------
__global__ __launch_bounds__(256)
void sim_gemm_sym(const float* __restrict__ E, float* __restrict__ S)
{
  __shared__ float As[32][132];
  __shared__ float Bs[32][132];
  const int tid = threadIdx.x;
  const int bx = blockIdx.x, by = blockIdx.y;
  if (bx < by) return;
  const int tx = tid & 15, ty = tid >> 4;
  const int r0 = by * 128, c0 = bx * 128;
  float acc[8][8] = {};

#pragma unroll
  for (int k0 = 0; k0 < ODIM; k0 += 32) {
#pragma unroll
    for (int l = 0; l < 4; ++l) {
      const int lin = l * 256 + tid;
      const int row = lin >> 3, q = lin & 7;
      const float4 a = *(const float4*)(E + (size_t)(r0 + row) * ODIM + k0 + q * 4);
      As[q + 0][row] = a.x; As[q + 8][row] = a.y;
      As[q + 16][row] = a.z; As[q + 24][row] = a.w;
      const float4 b = *(const float4*)(E + (size_t)(c0 + row) * ODIM + k0 + q * 4);
      Bs[q + 0][row] = b.x; Bs[q + 8][row] = b.y;
      Bs[q + 16][row] = b.z; Bs[q + 24][row] = b.w;
    }
    __syncthreads();
#pragma unroll
    for (int kk = 0; kk < 32; ++kk) {
      const int kp = ((kk & 3) << 3) | (kk >> 2);
      float a8[8], b8[8];
      *(float4*)&a8[0] = *(const float4*)&As[kp][ty * 8];
      *(float4*)&a8[4] = *(const float4*)&As[kp][ty * 8 + 4];
      *(float4*)&b8[0] = *(const float4*)&Bs[kp][tx * 4];
      *(float4*)&b8[4] = *(const float4*)&Bs[kp][64 + tx * 4];
#pragma unroll
      for (int i = 0; i < 8; ++i)
#pragma unroll
        for (int j = 0; j < 8; ++j)
          acc[i][j] = fmaf(a8[i], b8[j], acc[i][j]);
    }
    __syncthreads();
  }

#pragma unroll
  for (int i = 0; i < 8; ++i) {
    float4 o0, o1;
    o0.x = acc[i][0]; o0.y = acc[i][1]; o0.z = acc[i][2]; o0.w = acc[i][3];
    o1.x = acc[i][4]; o1.y = acc[i][5]; o1.z = acc[i][6]; o1.w = acc[i][7];
    float* dst = S + (size_t)(r0 + ty * 8 + i) * NROWS + c0;
    *(float4*)(dst + tx * 4) = o0;
    *(float4*)(dst + 64 + tx * 4) = o1;
  }

  if (bx == by) return;

#pragma unroll
  for (int h = 0; h < 2; ++h)
#pragma unroll
    for (int j = 0; j < 4; ++j) {
      const int col = c0 + h * 64 + tx * 4 + j;
      float4 a, b;
      a.x = acc[0][h * 4 + j]; a.y = acc[1][h * 4 + j];
      a.z = acc[2][h * 4 + j]; a.w = acc[3][h * 4 + j];
      b.x = acc[4][h * 4 + j]; b.y = acc[5][h * 4 + j];
      b.z = acc[6][h * 4 + j]; b.w = acc[7][h * 4 + j];
      float* dst = S + (size_t)col * NROWS + r0 + ty * 8;
      *(float4*)dst = a;
      *(float4*)(dst + 4) = b;
    }
}

// ---------------------------------------------------------------------------
// Per-row exact top-31 + masked rewrite. One BLOCK (256 thr = 4 waves) per
// row. Streaming load -> per-thread packed-u64 top-2 cache (values NOT kept
// in registers; rebuild re-reads global, rare). Each wave extracts its
// segment-local top-31 barrier-free (6-step shfl_xor butterfly, unique-
// winner pop, lane r keeps winner r). Rank-merge of 124 candidates in LDS
// (exact total order; packed keys unique), then zero + winner scatter.
// Order == (value desc, index asc) == jax.lax.top_k. 2 barriers total.
// ---------------------------------------------------------------------------
__device__ __forceinline__ uint32_t tokey(float f)
{
  const uint32_t u = __float_as_uint(f);
  return (u & 0x80000000u) ? ~u : (u | 0x80000000u);
}

__device__ __forceinline__ float relu_fromkey(uint32_t k)
{
  return (k > 0x80000000u) ? __uint_as_float(k & 0x7FFFFFFFu) : 0.f;
}

__device__ __forceinline__ uint64_t packkc(uint32_t key, uint32_t col)
{
  return ((uint64_t)key << 32) | (0xFFFFFFFFu - col);
}

__device__ __forceinline__ uint64_t shfl_xor_u64(uint64_t v, int m)
{
  const uint32_t lo = (uint32_t)__shfl_xor((int)(uint32_t)v, m, 64);
  const uint32_t hi = (uint32_t)__shfl_xor((int)(uint32_t)(v >> 32), m, 64);
  return ((uint64_t)hi << 32) | lo;
}

__device__ __forceinline__ void ins2p(uint64_t p, uint64_t& c0, uint64_t& c1)
{
  if (p > c1) {
    if (p > c0) { c1 = c0; c0 = p; }
    else c1 = p;
  }
}

__global__ __launch_bounds__(256)
void topk_mask(float* __restrict__ S)
{
  __shared__ uint64_t cand[4 * TOPK];

  const int tid = threadIdx.x;
  const int lane = tid & 63;
  const int w = tid >> 6;
  const int row = blockIdx.x;
  float* Srow = S + (size_t)row * NROWS;

  // streaming top-2 build over own 48 columns (c = tid*4 + j + i*1024)
  uint64_t c0 = 0, c1 = 0;
#pragma unroll
  for (int i = 0; i < 12; ++i) {
    const float4 f = *(const float4*)(Srow + tid * 4 + i * 1024);
    const uint32_t cb = tid * 4 + i * 1024;
    ins2p(packkc(tokey(f.x), cb + 0), c0, c1);
    ins2p(packkc(tokey(f.y), cb + 1), c0, c1);
    ins2p(packkc(tokey(f.z), cb + 2), c0, c1);
    ins2p(packkc(tokey(f.w), cb + 3), c0, c1);
  }

  // wave-local top-31 extraction, barrier-free
  uint64_t dead = 0;        // 48-bit dead mask over own slots
  uint64_t mywin = 0;       // lane r holds segment winner r
#pragma unroll 1
  for (int r = 0; r < TOPK; ++r) {
    uint64_t best = c0;
#pragma unroll
    for (int o = 1; o < 64; o <<= 1) {
      const uint64_t v = shfl_xor_u64(best, o);
      if (v > best) best = v;
    }
    if (lane == r) mywin = best;
    if (c0 == best) {                       // unique winner lane pops
      const uint32_t col = 0xFFFFFFFFu - (uint32_t)best;
      dead |= 1ull << (((col >> 10) << 2) | (col & 3));
      c0 = c1; c1 = 0;
      if (c0 == 0) {                        // lazy rebuild (rare, L2-hot)
#pragma unroll
        for (int i = 0; i < 12; ++i) {
          const float4 f = *(const float4*)(Srow + tid * 4 + i * 1024);
          const uint32_t cb = tid * 4 + i * 1024;
          if (!((dead >> (i * 4 + 0)) & 1ull)) ins2p(packkc(tokey(f.x), cb + 0), c0, c1);
          if (!((dead >> (i * 4 + 1)) & 1ull)) ins2p(packkc(tokey(f.y), cb + 1), c0, c1);
          if (!((dead >> (i * 4 + 2)) & 1ull)) ins2p(packkc(tokey(f.z), cb + 2), c0, c1);
          if (!((dead >> (i * 4 + 3)) & 1ull)) ins2p(packkc(tokey(f.w), cb + 3), c0, c1);
        }
      }
    }
  }

  if (lane < TOPK) cand[w * TOPK + lane] = mywin;
  __syncthreads();

  // exact rank-merge of 124 candidates (keys unique -> strict total order)
  uint64_t myc = 0; bool iswin = false;
  if (tid < 4 * TOPK) {
    myc = cand[tid];
    int rank = 0;
    for (int j = 0; j < 4 * TOPK; ++j) rank += (cand[j] > myc) ? 1 : 0;
    iswin = (rank < TOPK);
  }

  // zero own columns, then scatter the 31 winners
  const float4 z = {0.f, 0.f, 0.f, 0.f};
#pragma unroll
  for (int i = 0; i < 12; ++i)
    *(float4*)(Srow + tid * 4 + i * 1024) = z;
  __syncthreads();
  if (iswin) {
    const uint32_t col = 0xFFFFFFFFu - (uint32_t)myc;
    Srow[col] = relu_fromkey((uint32_t)(myc >> 32));
  }
}

// ---------------------------------------------------------------------------
extern "C" void kernel_launch(void* const* d_in, const int* in_sizes, int n_in,
                              void* d_out, int out_size, void* d_ws, size_t ws_size,
                              hipStream_t stream)
{
  const float* feat = (const float*)d_in[0];
  const float* W1 = (const float*)d_in[1];
  const float* b1 = (const float*)d_in[2];
  const float* W2 = (const float*)d_in[3];
  const float* b2 = (const float*)d_in[4];
  const float* W3 = (const float*)d_in[5];
  const float* b3 = (const float*)d_in[6];
  float* S = (float*)d_out;   // full sim matrix in d_out, masked in place

  // d_ws (62.9 MB): X1, X2, E
  float* X1 = (float*)d_ws;                          // 25.2 MB
  float* X2 = X1 + (size_t)NROWS * HDIM;             // 25.2 MB
  float* E  = X2 + (size_t)NROWS * HDIM;             // 12.6 MB

  gemm_big_nt<true><<<dim3(HDIM / 128, NROWS / 128), 256, 0, stream>>>(
      feat, W1, b1, X1, HDIM, FDIM);
  gemm_big_nt<true><<<dim3(HDIM / 128, NROWS / 128), 256, 0, stream>>>(
      X1, W2, b2, X2, HDIM, HDIM);
  gemm_nt_serial<false><<<dim3(ODIM / 64, NROWS / 64), 256, 0, stream>>>(
      X2, W3, b3, E, ODIM, HDIM);
  l2norm_np<<<NROWS / 64, 64, 0, stream>>>(E);
  sim_gemm_sym<<<dim3(NROWS / 128, NROWS / 128), 256, 0, stream>>>(E, S);
  topk_mask<<<NROWS, 256, 0, stream>>>(S);
}

// Round 16
// 1090.872 us; speedup vs baseline: 2.7776x; 2.7776x over previous
//
#include <hip/hip_runtime.h>
#include <cstdint>
#include <cstddef>

#define NROWS 12288
#define FDIM 768
#define HDIM 512
#define ODIM 256
#define TOPK 31                // knn_k + 1
#define CAP 1536               // candidate buffer bound (E[C] ~ 33)

// ---------------------------------------------------------------------------
// 64-tile fp32 GEMM (OpenBLAS-bitwise: serial ascending-k FMA chains, fold
// at K/2), swizzled LDS k-rows (conflict-free). Used for layer 3 (small N).
// ---------------------------------------------------------------------------
template<bool RELU>
__global__ __launch_bounds__(256)
void gemm_nt_serial(const float* __restrict__ A, const float* __restrict__ B,
                    const float* __restrict__ bias, float* __restrict__ C,
                    int Nout, int K)
{
  __shared__ float As[32][68];
  __shared__ float Bs[32][68];
  const int tid = threadIdx.x;
  const int tx = tid & 15, ty = tid >> 4;
  const int r0 = blockIdx.y * 64, c0 = blockIdx.x * 64;
  float acc[4][4] = {};
  float accC[4][4];
  bool first = true;
  const int Khalf = K / 2;

  for (int k0 = 0; k0 < K; k0 += 32) {
#pragma unroll
    for (int l = 0; l < 2; ++l) {
      const int lin = l * 256 + tid;
      const int row = lin >> 3, kq = lin & 7;
      const float4 a = *(const float4*)(A + (size_t)(r0 + row) * K + k0 + kq * 4);
      As[kq + 0][row] = a.x; As[kq + 8][row] = a.y;
      As[kq + 16][row] = a.z; As[kq + 24][row] = a.w;
      const float4 b = *(const float4*)(B + (size_t)(c0 + row) * K + k0 + kq * 4);
      Bs[kq + 0][row] = b.x; Bs[kq + 8][row] = b.y;
      Bs[kq + 16][row] = b.z; Bs[kq + 24][row] = b.w;
    }
    __syncthreads();
#pragma unroll
    for (int kk = 0; kk < 32; ++kk) {
      const int kp = ((kk & 3) << 3) | (kk >> 2);
      const float4 av = *(const float4*)&As[kp][ty * 4];
      const float4 bv = *(const float4*)&Bs[kp][tx * 4];
      const float a4[4] = {av.x, av.y, av.z, av.w};
      const float b4[4] = {bv.x, bv.y, bv.z, bv.w};
#pragma unroll
      for (int i = 0; i < 4; ++i)
#pragma unroll
        for (int j = 0; j < 4; ++j)
          acc[i][j] = fmaf(a4[i], b4[j], acc[i][j]);
    }
    __syncthreads();

    if ((k0 + 32 == Khalf) || (k0 + 32 == K)) {
#pragma unroll
      for (int i = 0; i < 4; ++i)
#pragma unroll
        for (int j = 0; j < 4; ++j) {
          accC[i][j] = first ? acc[i][j] : __fadd_rn(accC[i][j], acc[i][j]);
          acc[i][j] = 0.f;
        }
      first = false;
    }
  }

  const float4 bq = *(const float4*)(bias + c0 + tx * 4);
  const float bb[4] = {bq.x, bq.y, bq.z, bq.w};
#pragma unroll
  for (int i = 0; i < 4; ++i) {
    float v[4];
#pragma unroll
    for (int j = 0; j < 4; ++j) {
      v[j] = __fadd_rn(accC[i][j], bb[j]);
      if (RELU) v[j] = fmaxf(v[j], 0.f);
    }
    float4 o; o.x = v[0]; o.y = v[1]; o.z = v[2]; o.w = v[3];
    *(float4*)(C + (size_t)(r0 + ty * 4 + i) * Nout + c0 + tx * 4) = o;
  }
}

// ---------------------------------------------------------------------------
// 128-tile fp32 GEMM, 8x8 micro (split cols tx*4 / 64+tx*4), swizzled LDS,
// OpenBLAS-bitwise fold at K/2. Used for layers 1 and 2.
// ---------------------------------------------------------------------------
template<bool RELU>
__global__ __launch_bounds__(256)
void gemm_big_nt(const float* __restrict__ A, const float* __restrict__ B,
                 const float* __restrict__ bias, float* __restrict__ C,
                 int Nout, int K)
{
  __shared__ float As[32][132];
  __shared__ float Bs[32][132];
  const int tid = threadIdx.x;
  const int tx = tid & 15, ty = tid >> 4;
  const int r0 = blockIdx.y * 128, c0 = blockIdx.x * 128;
  float acc[8][8] = {};
  float accC[8][8];
  bool first = true;
  const int Khalf = K / 2;

  for (int k0 = 0; k0 < K; k0 += 32) {
#pragma unroll
    for (int l = 0; l < 4; ++l) {
      const int lin = l * 256 + tid;
      const int row = lin >> 3, q = lin & 7;
      const float4 a = *(const float4*)(A + (size_t)(r0 + row) * K + k0 + q * 4);
      As[q + 0][row] = a.x; As[q + 8][row] = a.y;
      As[q + 16][row] = a.z; As[q + 24][row] = a.w;
      const float4 b = *(const float4*)(B + (size_t)(c0 + row) * K + k0 + q * 4);
      Bs[q + 0][row] = b.x; Bs[q + 8][row] = b.y;
      Bs[q + 16][row] = b.z; Bs[q + 24][row] = b.w;
    }
    __syncthreads();
#pragma unroll
    for (int kk = 0; kk < 32; ++kk) {
      const int kp = ((kk & 3) << 3) | (kk >> 2);
      float a8[8], b8[8];
      *(float4*)&a8[0] = *(const float4*)&As[kp][ty * 8];
      *(float4*)&a8[4] = *(const float4*)&As[kp][ty * 8 + 4];
      *(float4*)&b8[0] = *(const float4*)&Bs[kp][tx * 4];
      *(float4*)&b8[4] = *(const float4*)&Bs[kp][64 + tx * 4];
#pragma unroll
      for (int i = 0; i < 8; ++i)
#pragma unroll
        for (int j = 0; j < 8; ++j)
          acc[i][j] = fmaf(a8[i], b8[j], acc[i][j]);
    }
    __syncthreads();

    if ((k0 + 32 == Khalf) || (k0 + 32 == K)) {
#pragma unroll
      for (int i = 0; i < 8; ++i)
#pragma unroll
        for (int j = 0; j < 8; ++j) {
          accC[i][j] = first ? acc[i][j] : __fadd_rn(accC[i][j], acc[i][j]);
          acc[i][j] = 0.f;
        }
      first = false;
    }
  }

  const float4 bq0 = *(const float4*)(bias + c0 + tx * 4);
  const float4 bq1 = *(const float4*)(bias + c0 + 64 + tx * 4);
  const float bb[8] = {bq0.x, bq0.y, bq0.z, bq0.w, bq1.x, bq1.y, bq1.z, bq1.w};
#pragma unroll
  for (int i = 0; i < 8; ++i) {
    float v[8];
#pragma unroll
    for (int j = 0; j < 8; ++j) {
      v[j] = __fadd_rn(accC[i][j], bb[j]);
      if (RELU) v[j] = fmaxf(v[j], 0.f);
    }
    float* dst = C + (size_t)(r0 + ty * 8 + i) * Nout + c0;
    float4 o0; o0.x = v[0]; o0.y = v[1]; o0.z = v[2]; o0.w = v[3];
    float4 o1; o1.x = v[4]; o1.y = v[5]; o1.z = v[6]; o1.w = v[7];
    *(float4*)(dst + tx * 4) = o0;
    *(float4*)(dst + 64 + tx * 4) = o1;
  }
}

// ---------------------------------------------------------------------------
// Row L2-normalize replicating numpy pairwise_sum bitwise (n=256) + IEEE
// sqrt/divide. One thread per row.
// ---------------------------------------------------------------------------
__global__ __launch_bounds__(64)
void l2norm_np(float* __restrict__ X)
{
  const int row = blockIdx.x * 64 + threadIdx.x;
  float* x = X + (size_t)row * ODIM;

  float S = 0.f;
#pragma unroll
  for (int h = 0; h < 2; ++h) {
    const float* a = x + h * 128;
    float r0 = __fmul_rn(a[0], a[0]);
    float r1 = __fmul_rn(a[1], a[1]);
    float r2 = __fmul_rn(a[2], a[2]);
    float r3 = __fmul_rn(a[3], a[3]);
    float r4 = __fmul_rn(a[4], a[4]);
    float r5 = __fmul_rn(a[5], a[5]);
    float r6 = __fmul_rn(a[6], a[6]);
    float r7 = __fmul_rn(a[7], a[7]);
    for (int i = 8; i < 128; i += 8) {
      r0 = __fadd_rn(r0, __fmul_rn(a[i + 0], a[i + 0]));
      r1 = __fadd_rn(r1, __fmul_rn(a[i + 1], a[i + 1]));
      r2 = __fadd_rn(r2, __fmul_rn(a[i + 2], a[i + 2]));
      r3 = __fadd_rn(r3, __fmul_rn(a[i + 3], a[i + 3]));
      r4 = __fadd_rn(r4, __fmul_rn(a[i + 4], a[i + 4]));
      r5 = __fadd_rn(r5, __fmul_rn(a[i + 5], a[i + 5]));
      r6 = __fadd_rn(r6, __fmul_rn(a[i + 6], a[i + 6]));
      r7 = __fadd_rn(r7, __fmul_rn(a[i + 7], a[i + 7]));
    }
    const float half = __fadd_rn(
        __fadd_rn(__fadd_rn(r0, r1), __fadd_rn(r2, r3)),
        __fadd_rn(__fadd_rn(r4, r5), __fadd_rn(r6, r7)));
    S = (h == 0) ? half : __fadd_rn(S, half);
  }

  const float d = fmaxf(__fsqrt_rn(S), 1e-12f);
  for (int k = 0; k < ODIM; ++k) x[k] = __fdiv_rn(x[k], d);
}

// ---------------------------------------------------------------------------
// SYMMETRIC fp32 sim GEMM: S = E @ E^T, upper-triangle blocks (bx >= by).
// Off-diagonal tiles mirrored directly from registers (8 consecutive rows
// per owned column -> two float4 stores). fmaf(a,b,c)==fmaf(b,a,c) ->
// mirrored chain bit-identical.
// ---------------------------------------------------------------------------
__global__ __launch_bounds__(256)
void sim_gemm_sym(const float* __restrict__ E, float* __restrict__ S)
{
  __shared__ float As[32][132];
  __shared__ float Bs[32][132];
  const int tid = threadIdx.x;
  const int bx = blockIdx.x, by = blockIdx.y;
  if (bx < by) return;
  const int tx = tid & 15, ty = tid >> 4;
  const int r0 = by * 128, c0 = bx * 128;
  float acc[8][8] = {};

#pragma unroll
  for (int k0 = 0; k0 < ODIM; k0 += 32) {
#pragma unroll
    for (int l = 0; l < 4; ++l) {
      const int lin = l * 256 + tid;
      const int row = lin >> 3, q = lin & 7;
      const float4 a = *(const float4*)(E + (size_t)(r0 + row) * ODIM + k0 + q * 4);
      As[q + 0][row] = a.x; As[q + 8][row] = a.y;
      As[q + 16][row] = a.z; As[q + 24][row] = a.w;
      const float4 b = *(const float4*)(E + (size_t)(c0 + row) * ODIM + k0 + q * 4);
      Bs[q + 0][row] = b.x; Bs[q + 8][row] = b.y;
      Bs[q + 16][row] = b.z; Bs[q + 24][row] = b.w;
    }
    __syncthreads();
#pragma unroll
    for (int kk = 0; kk < 32; ++kk) {
      const int kp = ((kk & 3) << 3) | (kk >> 2);
      float a8[8], b8[8];
      *(float4*)&a8[0] = *(const float4*)&As[kp][ty * 8];
      *(float4*)&a8[4] = *(const float4*)&As[kp][ty * 8 + 4];
      *(float4*)&b8[0] = *(const float4*)&Bs[kp][tx * 4];
      *(float4*)&b8[4] = *(const float4*)&Bs[kp][64 + tx * 4];
#pragma unroll
      for (int i = 0; i < 8; ++i)
#pragma unroll
        for (int j = 0; j < 8; ++j)
          acc[i][j] = fmaf(a8[i], b8[j], acc[i][j]);
    }
    __syncthreads();
  }

#pragma unroll
  for (int i = 0; i < 8; ++i) {
    float4 o0, o1;
    o0.x = acc[i][0]; o0.y = acc[i][1]; o0.z = acc[i][2]; o0.w = acc[i][3];
    o1.x = acc[i][4]; o1.y = acc[i][5]; o1.z = acc[i][6]; o1.w = acc[i][7];
    float* dst = S + (size_t)(r0 + ty * 8 + i) * NROWS + c0;
    *(float4*)(dst + tx * 4) = o0;
    *(float4*)(dst + 64 + tx * 4) = o1;
  }

  if (bx == by) return;

#pragma unroll
  for (int h = 0; h < 2; ++h)
#pragma unroll
    for (int j = 0; j < 4; ++j) {
      const int col = c0 + h * 64 + tx * 4 + j;
      float4 a, b;
      a.x = acc[0][h * 4 + j]; a.y = acc[1][h * 4 + j];
      a.z = acc[2][h * 4 + j]; a.w = acc[3][h * 4 + j];
      b.x = acc[4][h * 4 + j]; b.y = acc[5][h * 4 + j];
      b.z = acc[6][h * 4 + j]; b.w = acc[7][h * 4 + j];
      float* dst = S + (size_t)col * NROWS + r0 + ty * 8;
      *(float4*)dst = a;
      *(float4*)(dst + 4) = b;
    }
}

// ---------------------------------------------------------------------------
// Per-row exact top-31 via THRESHOLD + COMPACTION (no serial extraction).
// One block (256 thr) per row; 48 keys/thread kept in VGPRs.
//  1. per-thread max (packed u64: key<<32 | ~col — unique, exact order)
//  2. L = 31st-largest of the 256 maxima (parallel rank-compare in LDS).
//     Guarantees: count(keys >= L) >= 31 and true 31st key T* >= L, so all
//     winners are candidates.  E[count] ~ 33.
//  3. count + compact candidates >= L into LDS (binary-search fallback keeps
//     count <= CAP; unique keys guarantee termination; exact in all cases).
//  4. exact rank-select: ranks unique -> wlist[rank] = cand (no atomics).
//  5. zero own columns, barrier, scatter 31 winners.
// ~6 barriers total; no dependent shuffle chains.
// ---------------------------------------------------------------------------
__device__ __forceinline__ uint32_t tokey(float f)
{
  const uint32_t u = __float_as_uint(f);
  return (u & 0x80000000u) ? ~u : (u | 0x80000000u);
}

__device__ __forceinline__ float relu_fromkey(uint32_t k)
{
  return (k > 0x80000000u) ? __uint_as_float(k & 0x7FFFFFFFu) : 0.f;
}

__device__ __forceinline__ uint64_t packkc(uint32_t key, uint32_t col)
{
  return ((uint64_t)key << 32) | (0xFFFFFFFFu - col);
}

__global__ __launch_bounds__(256)
void topk_mask(float* __restrict__ S)
{
  __shared__ uint64_t c0s[256];
  __shared__ uint64_t cand[CAP];
  __shared__ uint64_t wlist[TOPK];
  __shared__ uint64_t Lsh;
  __shared__ int cnt_sh, pos_sh;

  const int tid = threadIdx.x;
  const int row = blockIdx.x;
  float* Srow = S + (size_t)row * NROWS;

  // 1. load + convert (keys stay in VGPRs), per-thread max
  uint4 kq[12];
  uint64_t c0 = 0;
#pragma unroll
  for (int i = 0; i < 12; ++i) {
    const float4 f = *(const float4*)(Srow + tid * 4 + i * 1024);
    const uint32_t cb = tid * 4 + i * 1024;
    uint4 k;
    k.x = tokey(f.x); k.y = tokey(f.y); k.z = tokey(f.z); k.w = tokey(f.w);
    kq[i] = k;
    uint64_t p;
    p = packkc(k.x, cb + 0); if (p > c0) c0 = p;
    p = packkc(k.y, cb + 1); if (p > c0) c0 = p;
    p = packkc(k.z, cb + 2); if (p > c0) c0 = p;
    p = packkc(k.w, cb + 3); if (p > c0) c0 = p;
  }
  c0s[tid] = c0;
  if (tid == 0) cnt_sh = 0;
  __syncthreads();

  // 2. L = 31st largest of the 256 maxima (ranks unique)
  int rank = 0;
  for (int j = 0; j < 256; ++j) rank += (c0s[j] > c0) ? 1 : 0;
  if (rank == TOPK - 1) Lsh = c0;
  __syncthreads();
  uint64_t L = Lsh;

  // 3a. count candidates
  int my = 0;
#pragma unroll
  for (int i = 0; i < 12; ++i) {
    const uint32_t cb = tid * 4 + i * 1024;
    my += (packkc(kq[i].x, cb + 0) >= L) ? 1 : 0;
    my += (packkc(kq[i].y, cb + 1) >= L) ? 1 : 0;
    my += (packkc(kq[i].z, cb + 2) >= L) ? 1 : 0;
    my += (packkc(kq[i].w, cb + 3) >= L) ? 1 : 0;
  }
  atomicAdd(&cnt_sh, my);
  __syncthreads();
  int C = cnt_sh;

  // 3b. fallback (essentially never runs; exactness preserved)
  uint64_t hi = 0xFFFFFFFFFFFFFFFFull;
  while (C > CAP) {
    const uint64_t mid = L + ((hi - L) >> 1);
    if (tid == 0) cnt_sh = 0;
    __syncthreads();
    int m2 = 0;
#pragma unroll
    for (int i = 0; i < 12; ++i) {
      const uint32_t cb = tid * 4 + i * 1024;
      m2 += (packkc(kq[i].x, cb + 0) >= mid) ? 1 : 0;
      m2 += (packkc(kq[i].y, cb + 1) >= mid) ? 1 : 0;
      m2 += (packkc(kq[i].z, cb + 2) >= mid) ? 1 : 0;
      m2 += (packkc(kq[i].w, cb + 3) >= mid) ? 1 : 0;
    }
    atomicAdd(&cnt_sh, m2);
    __syncthreads();
    const int c2 = cnt_sh;
    if (c2 >= TOPK) { L = mid; C = c2; my = m2; } else { hi = mid; }
    __syncthreads();
  }

  // 3c. compact candidates into LDS
  if (tid == 0) pos_sh = 0;
  __syncthreads();
  int base = (my > 0) ? atomicAdd(&pos_sh, my) : 0;
#pragma unroll
  for (int i = 0; i < 12; ++i) {
    const uint32_t cb = tid * 4 + i * 1024;
    uint64_t p;
    p = packkc(kq[i].x, cb + 0); if (p >= L) cand[base++] = p;
    p = packkc(kq[i].y, cb + 1); if (p >= L) cand[base++] = p;
    p = packkc(kq[i].z, cb + 2); if (p >= L) cand[base++] = p;
    p = packkc(kq[i].w, cb + 3); if (p >= L) cand[base++] = p;
  }
  __syncthreads();

  // 4. exact rank-select (ranks unique -> direct wlist placement)
  for (int idx = tid; idx < C; idx += 256) {
    const uint64_t p = cand[idx];
    int r = 0;
    for (int j = 0; j < C; ++j) r += (cand[j] > p) ? 1 : 0;
    if (r < TOPK) wlist[r] = p;
  }

  // 5. zero own columns, then scatter winners
  const float4 z = {0.f, 0.f, 0.f, 0.f};
#pragma unroll
  for (int i = 0; i < 12; ++i)
    *(float4*)(Srow + tid * 4 + i * 1024) = z;
  __syncthreads();
  if (tid < TOPK) {
    const uint64_t p = wlist[tid];
    const uint32_t col = 0xFFFFFFFFu - (uint32_t)p;
    Srow[col] = relu_fromkey((uint32_t)(p >> 32));
  }
}

// ---------------------------------------------------------------------------
extern "C" void kernel_launch(void* const* d_in, const int* in_sizes, int n_in,
                              void* d_out, int out_size, void* d_ws, size_t ws_size,
                              hipStream_t stream)
{
  const float* feat = (const float*)d_in[0];
  const float* W1 = (const float*)d_in[1];
  const float* b1 = (const float*)d_in[2];
  const float* W2 = (const float*)d_in[3];
  const float* b2 = (const float*)d_in[4];
  const float* W3 = (const float*)d_in[5];
  const float* b3 = (const float*)d_in[6];
  float* S = (float*)d_out;   // full sim matrix in d_out, masked in place

  // d_ws (62.9 MB): X1, X2, E
  float* X1 = (float*)d_ws;                          // 25.2 MB
  float* X2 = X1 + (size_t)NROWS * HDIM;             // 25.2 MB
  float* E  = X2 + (size_t)NROWS * HDIM;             // 12.6 MB

  gemm_big_nt<true><<<dim3(HDIM / 128, NROWS / 128), 256, 0, stream>>>(
      feat, W1, b1, X1, HDIM, FDIM);
  gemm_big_nt<true><<<dim3(HDIM / 128, NROWS / 128), 256, 0, stream>>>(
      X1, W2, b2, X2, HDIM, HDIM);
  gemm_nt_serial<false><<<dim3(ODIM / 64, NROWS / 64), 256, 0, stream>>>(
      X2, W3, b3, E, ODIM, HDIM);
  l2norm_np<<<NROWS / 64, 64, 0, stream>>>(E);
  sim_gemm_sym<<<dim3(NROWS / 128, NROWS / 128), 256, 0, stream>>>(E, S);
  topk_mask<<<NROWS, 256, 0, stream>>>(S);
}